// Round 1
// baseline (134.596 us; speedup 1.0000x reference)
//
#include <hip/hip_runtime.h>
#include <hip/hip_bf16.h>

#define IN_C 512
#define HID_C 128
#define OUT_C 16

// ---------------------------------------------------------------------------
// Folded weights: Wc[o][k] = sum_h W2[o][h] * W1[h][k]   (16 x 512)
//                 cconst[o] = b2[o] + sum_h b1[h] * W2[o][h]
// ---------------------------------------------------------------------------
__global__ void prep_kernel(const float* __restrict__ W1, const float* __restrict__ b1,
                            const float* __restrict__ W2, const float* __restrict__ b2,
                            float* __restrict__ Wc, float* __restrict__ cconst) {
    if (blockIdx.x < 32) {
        int idx = blockIdx.x * 256 + threadIdx.x;   // 0 .. 8191
        int o = idx >> 9;                            // /512
        int k = idx & 511;
        float s = 0.f;
#pragma unroll 8
        for (int h = 0; h < HID_C; ++h)
            s = fmaf(W2[o * HID_C + h], W1[h * IN_C + k], s);
        Wc[o * IN_C + k] = s;
    } else if (threadIdx.x < OUT_C) {
        int o = threadIdx.x;
        float s = b2[o];
        for (int h = 0; h < HID_C; ++h)
            s = fmaf(b1[h], W2[o * HID_C + h], s);
        cconst[o] = s;
    }
}

// deg[c] += 1 for each edge's col
__global__ void deg_kernel(const int* __restrict__ ei, float* __restrict__ dsq, int E) {
    int e = blockIdx.x * 256 + threadIdx.x;
    if (e < E) {
        int c = ei[E + e];
        unsafeAtomicAdd(&dsq[c], 1.0f);
    }
}

__global__ void sqrt_kernel(float* __restrict__ dsq, int N) {
    int n = blockIdx.x * 256 + threadIdx.x;
    if (n < N) dsq[n] = sqrtf(dsq[n]);
}

// ---------------------------------------------------------------------------
// h2 = x @ Wc^T   [N,16].  One wave per row; Wc lives in 128 VGPRs (no LDS).
// Lane l covers k in {4l..4l+3} U {256+4l..256+4l+3}.
// 16 partials reduced across 64 lanes via halving exchange (15+2 shuffles).
// ---------------------------------------------------------------------------
__global__ __launch_bounds__(256, 2) void h2_kernel(const float* __restrict__ x,
                                                    const float* __restrict__ Wc,
                                                    float* __restrict__ h2, int N) {
    const int lane = threadIdx.x & 63;
    const int gw = (blockIdx.x * 256 + threadIdx.x) >> 6;
    const int nw = (gridDim.x * 256) >> 6;

    float4 w0[16], w1[16];
#pragma unroll
    for (int o = 0; o < 16; ++o) {
        w0[o] = *(const float4*)(Wc + o * IN_C + 4 * lane);
        w1[o] = *(const float4*)(Wc + o * IN_C + 256 + 4 * lane);
    }

    for (int r = gw; r < N; r += nw) {
        const float4 a0 = *(const float4*)(x + (size_t)r * IN_C + 4 * lane);
        const float4 a1 = *(const float4*)(x + (size_t)r * IN_C + 256 + 4 * lane);
        float p[16];
#pragma unroll
        for (int o = 0; o < 16; ++o) {
            float s = a0.x * w0[o].x;
            s = fmaf(a0.y, w0[o].y, s);
            s = fmaf(a0.z, w0[o].z, s);
            s = fmaf(a0.w, w0[o].w, s);
            s = fmaf(a1.x, w1[o].x, s);
            s = fmaf(a1.y, w1[o].y, s);
            s = fmaf(a1.z, w1[o].z, s);
            s = fmaf(a1.w, w1[o].w, s);
            p[o] = s;
        }
        // halving-exchange reduction: after 4 steps lane group-of-16 holds one
        // output each; output index = bit-reversed low 4 lane bits.
#define RSTEP(MASK, HALF)                                            \
        {                                                            \
            const bool hi = (lane & MASK) != 0;                      \
            _Pragma("unroll")                                        \
            for (int i = 0; i < HALF; ++i) {                         \
                float send = hi ? p[i] : p[i + HALF];                \
                float recv = __shfl_xor(send, MASK, 64);             \
                float keep = hi ? p[i + HALF] : p[i];                \
                p[i] = keep + recv;                                  \
            }                                                        \
        }
        RSTEP(1, 8)
        RSTEP(2, 4)
        RSTEP(4, 2)
        RSTEP(8, 1)
#undef RSTEP
        float v = p[0];
        v += __shfl_xor(v, 16, 64);
        v += __shfl_xor(v, 32, 64);
        if (lane < 16) {
            int o = ((lane & 1) << 3) | ((lane & 2) << 1) | ((lane & 4) >> 1) | ((lane & 8) >> 3);
            h2[(size_t)r * 16 + o] = v;
        }
    }
}

__global__ void init_out_kernel(const float* __restrict__ cconst, float* __restrict__ out, int total) {
    int i = blockIdx.x * 256 + threadIdx.x;
    if (i < total) out[i] = cconst[i & 15];
}

// out[col][o] += d[row]*d[col] * h2[row][o]   (16 lanes per edge)
__global__ void edge_kernel(const int* __restrict__ ei, const float* __restrict__ dsq,
                            const float* __restrict__ h2, float* __restrict__ out, int E) {
    int t = blockIdx.x * 256 + threadIdx.x;
    int e = t >> 4;
    if (e < E) {
        int o = t & 15;
        int r = ei[e];
        int c = ei[E + e];
        float w = dsq[r] * dsq[c];
        float v = w * h2[r * 16 + o];
        unsafeAtomicAdd(&out[c * 16 + o], v);
    }
}

// ---------------------------------------------------------------------------
extern "C" void kernel_launch(void* const* d_in, const int* in_sizes, int n_in,
                              void* d_out, int out_size, void* d_ws, size_t ws_size,
                              hipStream_t stream) {
    const float* x  = (const float*)d_in[0];
    const int*   ei = (const int*)d_in[1];
    const float* W1 = (const float*)d_in[2];
    const float* b1 = (const float*)d_in[3];
    const float* W2 = (const float*)d_in[4];
    const float* b2 = (const float*)d_in[5];
    float* out = (float*)d_out;

    const int N = in_sizes[0] / IN_C;
    const int E = in_sizes[1] / 2;

    // workspace layout (floats): Wc[16*512] | cconst[16] | dsq[N] | h2[N*16]
    float* ws     = (float*)d_ws;
    float* Wc     = ws;
    float* cconst = ws + 16 * IN_C;
    float* dsq    = cconst + 16;
    float* h2     = dsq + N;
    // total: (8208 + 17*N)*4 bytes ~ 3.5 MB

    hipLaunchKernelGGL(prep_kernel, dim3(33), dim3(256), 0, stream, W1, b1, W2, b2, Wc, cconst);
    hipMemsetAsync(dsq, 0, (size_t)N * sizeof(float), stream);
    hipLaunchKernelGGL(deg_kernel, dim3((E + 255) / 256), dim3(256), 0, stream, ei, dsq, E);
    hipLaunchKernelGGL(sqrt_kernel, dim3((N + 255) / 256), dim3(256), 0, stream, dsq, N);
    hipLaunchKernelGGL(h2_kernel, dim3(512), dim3(256), 0, stream, x, Wc, h2, N);
    hipLaunchKernelGGL(init_out_kernel, dim3((out_size + 255) / 256), dim3(256), 0, stream, cconst, out, out_size);
    hipLaunchKernelGGL(edge_kernel, dim3((E * 16 + 255) / 256), dim3(256), 0, stream, ei, dsq, h2, out, E);
}